// Round 2
// baseline (213.331 us; speedup 1.0000x reference)
//
#include <hip/hip_runtime.h>

// (B,C,L,H,W) = (4,64,16,32,32), K=1024, D=C=64
constexpr int Cc   = 64;
constexpr int Kc   = 1024;
constexpr int Dc   = 64;
constexpr int LHWc = 16 * 32 * 32;        // 16384
constexpr int Nc   = 4 * LHWc;            // 65536 vectors
constexpr int QSIZE    = 4 * Cc * LHWc;   // 4194304
constexpr int OFF_LOSS = QSIZE;           // 4194304
constexpr int OFF_IDX  = QSIZE + 1;       // 4194305

constexpr int BLK_ROWS = 64;              // rows per block
constexpr int XPAD     = 68;              // LDS row stride (16B aligned)

typedef __attribute__((ext_vector_type(8))) short short8;   // 8 x bf16 bits
typedef __attribute__((ext_vector_type(4))) float f32x4;

static __device__ __forceinline__ unsigned short f2bf(float f) {
    unsigned u = __float_as_uint(f);
    u += 0x7FFFu + ((u >> 16) & 1u);      // RNE (finite data only)
    return (unsigned short)(u >> 16);
}
static __device__ __forceinline__ float bf2f(unsigned short h) {
    return __uint_as_float(((unsigned)h) << 16);
}

// Prep: zero loss; split codebook into bf16 hi/lo; exact-chain c2.
__global__ void vq_prep(const float* __restrict__ cb, float* __restrict__ out,
                        unsigned short* __restrict__ cbh,
                        unsigned short* __restrict__ cbl,
                        float* __restrict__ c2)
{
    const int k = blockIdx.x * 256 + threadIdx.x;
    if (k == 0) out[OFF_LOSS] = 0.0f;
    if (k >= Kc) return;
    const float* c = cb + (size_t)k * Dc;
    float s = 0.f;
#pragma unroll
    for (int d = 0; d < Dc; ++d) {
        float v = c[d];
        s = __builtin_fmaf(v, v, s);
        unsigned short h = f2bf(v);
        cbh[(size_t)k * Dc + d] = h;
        cbl[(size_t)k * Dc + d] = f2bf(v - bf2f(h));
    }
    c2[k] = s;
}

__global__ __launch_bounds__(512, 4) void vq_main(
    const float* __restrict__ in, const float* __restrict__ codebook,
    const unsigned short* __restrict__ cbh,
    const unsigned short* __restrict__ cbl,
    const float* __restrict__ c2g, float* __restrict__ out)
{
    __shared__ float    xs[BLK_ROWS][XPAD];
    __shared__ float    xs2[BLK_ROWS];
    __shared__ float    c2bs[Kc];            // c2 + 0.25 bias (approx ordering)
    __shared__ unsigned cand[BLK_ROWS][4];   // per row, per K-quarter: bK | sK<<16
    __shared__ int      kws[BLK_ROWS];

    const int tid  = threadIdx.x;
    const int lane = tid & 63;
    const int w    = __builtin_amdgcn_readfirstlane(tid >> 6);
    const int col  = lane & 15;           // MFMA n / A-row lane index
    const int g    = lane >> 4;           // MFMA k-slot group
    const int rg   = w >> 2;              // row-group (0..1): 32 rows each
    const int qq   = w & 3;               // K-quarter (0..3): 256 codes each
    const int wrow0 = rg * 32;
    const int kbase = qq * 256;

    const int bq = blockIdx.x >> 8;                    // batch index (256 blk/batch)
    const int p0 = (blockIdx.x & 255) * BLK_ROWS;      // LHW offset
    const size_t inBase = (size_t)bq * (Cc * LHWc) + p0;

    // ---- stage biased c2 into LDS (positive approx-ordering values) ----
    c2bs[tid]       = c2g[tid] + 0.25f;
    c2bs[tid + 512] = c2g[tid + 512] + 0.25f;

    // ---- stage X[64 rows][64 d] into LDS (coalesced) ----
#pragma unroll
    for (int i = 0; i < 8; ++i) {
        int idx = i * 512 + tid;
        int d = idx >> 6, row = idx & 63;
        xs[row][d] = in[inBase + (size_t)d * LHWc + row];
    }
    __syncthreads();

    // ---- x2 per row: exact ascending fma chain (used only in recheck) ----
    if (tid < BLK_ROWS) {
        float s = 0.f;
#pragma unroll
        for (int d = 0; d < Dc; ++d) s = __builtin_fmaf(xs[tid][d], xs[tid][d], s);
        xs2[tid] = s;
    }

    // ---- build A fragments (bf16 hi/lo split) ----
    short8 xh[2][2], xl[2][2];   // [row-tile][kt]
#pragma unroll
    for (int t = 0; t < 2; ++t) {
#pragma unroll
        for (int kt = 0; kt < 2; ++kt) {
            const float* px = &xs[wrow0 + t * 16 + col][kt * 32 + g * 8];
            f32x4 v0 = *(const f32x4*)px;
            f32x4 v1 = *(const f32x4*)(px + 4);
            short8 h8, l8;
#pragma unroll
            for (int j = 0; j < 4; ++j) {
                unsigned short ha = f2bf(v0[j]);
                h8[j]     = (short)ha;
                l8[j]     = (short)f2bf(v0[j] - bf2f(ha));
                unsigned short hb = f2bf(v1[j]);
                h8[4 + j] = (short)hb;
                l8[4 + j] = (short)f2bf(v1[j] - bf2f(hb));
            }
            xh[t][kt] = h8; xl[t][kt] = l8;
        }
    }

    // ---- streaming top-2 state per (tile, reg) slot ----
    float bV[2][4], sV[2][4];
    int   bK[2][4], sK[2][4];
#pragma unroll
    for (int t = 0; t < 2; ++t)
#pragma unroll
        for (int r = 0; r < 4; ++r) {
            bV[t][r] = 3.4e38f; sV[t][r] = 3.4e38f; bK[t][r] = 0; sK[t][r] = 0;
        }

    const unsigned short* bhp = cbh + (size_t)(kbase + col) * Dc + g * 8;
    const unsigned short* blp = cbl + (size_t)(kbase + col) * Dc + g * 8;

    short8 bh0 = *(const short8*)(bhp);
    short8 bh1 = *(const short8*)(bhp + 32);
    short8 bl0 = *(const short8*)(blp);
    short8 bl1 = *(const short8*)(blp + 32);

    int kcolv = kbase + col;

#pragma unroll 1
    for (int ct = 0; ct < 16; ++ct) {
        const float c2bv = c2bs[kcolv];      // issued early, hides under MFMA
        short8 ch0 = bh0, ch1 = bh1, cl0 = bl0, cl1 = bl1;
        bhp += 16 * Dc; blp += 16 * Dc;
        if (ct < 15) {                       // 1-deep register prefetch
            bh0 = *(const short8*)(bhp);
            bh1 = *(const short8*)(bhp + 32);
            bl0 = *(const short8*)(blp);
            bl1 = *(const short8*)(blp + 32);
        }

        f32x4 acc0 = {0.f, 0.f, 0.f, 0.f};
        f32x4 acc1 = {0.f, 0.f, 0.f, 0.f};
        // interleaved acc0/acc1: dependent-MFMA distance 2
        acc0 = __builtin_amdgcn_mfma_f32_16x16x32_bf16(xh[0][0], ch0, acc0, 0, 0, 0);
        acc1 = __builtin_amdgcn_mfma_f32_16x16x32_bf16(xh[1][0], ch0, acc1, 0, 0, 0);
        acc0 = __builtin_amdgcn_mfma_f32_16x16x32_bf16(xh[0][1], ch1, acc0, 0, 0, 0);
        acc1 = __builtin_amdgcn_mfma_f32_16x16x32_bf16(xh[1][1], ch1, acc1, 0, 0, 0);
        acc0 = __builtin_amdgcn_mfma_f32_16x16x32_bf16(xh[0][0], cl0, acc0, 0, 0, 0);
        acc1 = __builtin_amdgcn_mfma_f32_16x16x32_bf16(xh[1][0], cl0, acc1, 0, 0, 0);
        acc0 = __builtin_amdgcn_mfma_f32_16x16x32_bf16(xh[0][1], cl1, acc0, 0, 0, 0);
        acc1 = __builtin_amdgcn_mfma_f32_16x16x32_bf16(xh[1][1], cl1, acc1, 0, 0, 0);
        acc0 = __builtin_amdgcn_mfma_f32_16x16x32_bf16(xl[0][0], ch0, acc0, 0, 0, 0);
        acc1 = __builtin_amdgcn_mfma_f32_16x16x32_bf16(xl[1][0], ch0, acc1, 0, 0, 0);
        acc0 = __builtin_amdgcn_mfma_f32_16x16x32_bf16(xl[0][1], ch1, acc0, 0, 0, 0);
        acc1 = __builtin_amdgcn_mfma_f32_16x16x32_bf16(xl[1][1], ch1, acc1, 0, 0, 0);

        // argmin_k d2 == argmin_k (c2[k]+0.25 - 2*dot): x2 folded out
#pragma unroll
        for (int t = 0; t < 2; ++t) {
#pragma unroll
            for (int r = 0; r < 4; ++r) {
                float a  = (t == 0) ? acc0[r] : acc1[r];
                float v  = __builtin_fmaf(-2.f, a, c2bv);
                bool  c1 = v < bV[t][r];
                float nb  = c1 ? v : bV[t][r];
                int   nbk = c1 ? kcolv : bK[t][r];
                float mx  = c1 ? bV[t][r] : v;
                int   mxk = c1 ? bK[t][r] : kcolv;
                bool  c2_ = mx < sV[t][r];
                sV[t][r] = c2_ ? mx : sV[t][r];
                sK[t][r] = c2_ ? mxk : sK[t][r];
                bV[t][r] = nb; bK[t][r] = nbk;
            }
        }
        kcolv += 16;
    }

    // ---- butterfly top-2 merge across the 16 lanes sharing a row ----
#pragma unroll
    for (int m = 1; m < 16; m <<= 1) {
#pragma unroll
        for (int t = 0; t < 2; ++t) {
#pragma unroll
            for (int r = 0; r < 4; ++r) {
                float ob  = __shfl_xor(bV[t][r], m, 64);
                int   obk = __shfl_xor(bK[t][r], m, 64);
                float os  = __shfl_xor(sV[t][r], m, 64);
                int   osk = __shfl_xor(sK[t][r], m, 64);
                bool  c1 = ob < bV[t][r];
                float nb  = c1 ? ob : bV[t][r];
                int   nbk = c1 ? obk : bK[t][r];
                float mx  = c1 ? bV[t][r] : ob;
                int   mxk = c1 ? bK[t][r] : obk;
                bool  c3 = os < sV[t][r];
                float ms  = c3 ? os : sV[t][r];
                int   msk = c3 ? osk : sK[t][r];
                bool  c4 = mx < ms;
                sV[t][r] = c4 ? mx : ms;
                sK[t][r] = c4 ? mxk : msk;
                bV[t][r] = nb; bK[t][r] = nbk;
            }
        }
    }
    if (col == 0) {
#pragma unroll
        for (int t = 0; t < 2; ++t)
#pragma unroll
            for (int r = 0; r < 4; ++r)
                cand[wrow0 + t * 16 + g * 4 + r][qq] =
                    (unsigned)bK[t][r] | ((unsigned)sK[t][r] << 16);
    }
    __syncthreads();

    // ---- exact recheck: 8 candidates/row, 1 thread per (row, candidate) ----
    {
        const int row = tid >> 3;
        const int ci  = tid & 7;
        const unsigned cd = cand[row][ci >> 1];
        const int k = (ci & 1) ? (int)(cd >> 16) : (int)(cd & 0xFFFFu);
        const float* cbr = codebook + (size_t)k * Dc;
        float a = 0.f;
#pragma unroll
        for (int d4 = 0; d4 < 16; ++d4) {
            f32x4 cv = *(const f32x4*)(cbr + d4 * 4);
            const float* xr = &xs[row][d4 * 4];
            a = __builtin_fmaf(xr[0], cv[0], a);
            a = __builtin_fmaf(xr[1], cv[1], a);
            a = __builtin_fmaf(xr[2], cv[2], a);
            a = __builtin_fmaf(xr[3], cv[3], a);
        }
        float d2 = __builtin_fmaf(-2.f, a, xs2[row]) + c2g[k];
        unsigned long long pk =
            ((unsigned long long)__float_as_uint(d2) << 32) | (unsigned)k;
#pragma unroll
        for (int m = 1; m < 8; m <<= 1) {
            unsigned long long o = __shfl_xor(pk, m, 64);
            pk = o < pk ? o : pk;            // min d2, ties -> lowest k
        }
        if (ci == 0) {
            const int kwin = (int)(pk & 0xFFFFFFFFu);
            kws[row] = kwin;
            out[OFF_IDX + (size_t)blockIdx.x * BLK_ROWS + row] = (float)kwin;
        }
    }
    __syncthreads();

    // ---- quantized write + loss: 8 threads per row, 8 channels each ----
    {
        const int row = tid & 63;
        const int cp  = tid >> 6;
        const int kw  = kws[row];
        const float* cbw = codebook + (size_t)kw * Dc + cp * 8;
        float* qout = out + inBase + row;
        float ls = 0.f;
#pragma unroll
        for (int j = 0; j < 8; ++j) {
            const int c = cp * 8 + j;
            float qv = cbw[j];
            qout[(size_t)c * LHWc] = qv;     // coalesced across lanes per c
            float e = qv - xs[row][c];
            ls = __builtin_fmaf(e, e, ls);
        }
#pragma unroll
        for (int off = 32; off > 0; off >>= 1) ls += __shfl_down(ls, off, 64);
        if (lane == 0) atomicAdd(&out[OFF_LOSS], ls * (1.25f / (float)QSIZE));
    }
}

extern "C" void kernel_launch(void* const* d_in, const int* in_sizes, int n_in,
                              void* d_out, int out_size, void* d_ws, size_t ws_size,
                              hipStream_t stream) {
    const float* in = (const float*)d_in[0];   // [4,64,16,32,32] f32
    const float* cb = (const float*)d_in[1];   // [1024,64] f32
    float* out = (float*)d_out;
    (void)in_sizes; (void)n_in; (void)out_size; (void)ws_size;

    unsigned short* cbh = (unsigned short*)d_ws;                 // 128 KB
    unsigned short* cbl = cbh + (size_t)Kc * Dc;                 // 128 KB
    float*          c2  = (float*)(cbl + (size_t)Kc * Dc);       // 4 KB

    vq_prep<<<dim3(Kc / 256), dim3(256), 0, stream>>>(cb, out, cbh, cbl, c2);
    vq_main<<<dim3(Nc / BLK_ROWS), dim3(512), 0, stream>>>(in, cb, cbh, cbl, c2, out);
}

// Round 3
// 184.245 us; speedup vs baseline: 1.1579x; 1.1579x over previous
//
#include <hip/hip_runtime.h>

// (B,C,L,H,W) = (4,64,16,32,32), K=1024, D=C=64
constexpr int Cc   = 64;
constexpr int Kc   = 1024;
constexpr int Dc   = 64;
constexpr int LHWc = 16 * 32 * 32;        // 16384
constexpr int Nc   = 4 * LHWc;            // 65536 vectors
constexpr int QSIZE    = 4 * Cc * LHWc;   // 4194304
constexpr int OFF_LOSS = QSIZE;           // 4194304
constexpr int OFF_IDX  = QSIZE + 1;       // 4194305

constexpr int BLK_ROWS = 128;             // rows per block
constexpr int XPAD     = 68;              // LDS row stride (16B aligned, bank-spread)

typedef __attribute__((ext_vector_type(8))) short short8;   // 8 x bf16 bits
typedef __attribute__((ext_vector_type(4))) float f32x4;

static __device__ __forceinline__ unsigned short f2bf(float f) {
    unsigned u = __float_as_uint(f);
    u += 0x7FFFu + ((u >> 16) & 1u);      // RNE (finite data only)
    return (unsigned short)(u >> 16);
}
static __device__ __forceinline__ float bf2f(unsigned short h) {
    return __uint_as_float(((unsigned)h) << 16);
}

// Prep: zero loss; split codebook into bf16 hi/lo (coalesced); exact-chain c2.
// 16 blocks x 256 threads; 64 codes per block.
__global__ __launch_bounds__(256) void vq_prep(
    const float* __restrict__ cb, float* __restrict__ out,
    unsigned short* __restrict__ cbh, unsigned short* __restrict__ cbl,
    float* __restrict__ c2)
{
    const int t  = threadIdx.x;
    const int k0 = blockIdx.x * 64;
    if (blockIdx.x == 0 && t == 0) out[OFF_LOSS] = 0.0f;

    // phase A: hi/lo split, fully coalesced (4 codes per round, 16 rounds)
    const int d  = t & 63;
#pragma unroll
    for (int r = 0; r < 16; ++r) {
        const int k = k0 + r * 4 + (t >> 6);
        const float v = cb[(size_t)k * Dc + d];
        unsigned short h = f2bf(v);
        cbh[(size_t)k * Dc + d] = h;
        cbl[(size_t)k * Dc + d] = f2bf(v - bf2f(h));
    }

    // phase B (independent): exact ascending fma chain for c2
    if (t < 64) {
        const int k = k0 + t;
        const float* c = cb + (size_t)k * Dc;
        float s = 0.f;
#pragma unroll
        for (int dd = 0; dd < Dc; ++dd) s = __builtin_fmaf(c[dd], c[dd], s);
        c2[k] = s;
    }
}

__global__ __launch_bounds__(512, 4) void vq_main(
    const float* __restrict__ in, const float* __restrict__ codebook,
    const unsigned short* __restrict__ cbh,
    const unsigned short* __restrict__ cbl,
    const float* __restrict__ c2g, float* __restrict__ out)
{
    __shared__ float    xs[BLK_ROWS][XPAD];
    __shared__ float    xs2[BLK_ROWS];
    __shared__ float    c2bs[Kc];            // c2 + 0.25 bias (approx ordering)
    __shared__ unsigned cand[BLK_ROWS][2];   // per row, per K-half: bK | sK<<16
    __shared__ int      kws[BLK_ROWS];

    const int tid  = threadIdx.x;
    const int lane = tid & 63;
    const int w    = __builtin_amdgcn_readfirstlane(tid >> 6);
    const int col  = lane & 15;           // MFMA n / A-row lane index
    const int g    = lane >> 4;           // MFMA k-slot group
    const int rg   = w >> 1;              // row-group (0..3): 32 rows each
    const int qq   = w & 1;               // K-half (0..1): 512 codes each
    const int wrow0 = rg * 32;
    const int kbase = qq * 512;

    const int bq = blockIdx.x >> 7;                    // batch (128 blk/batch)
    const int p0 = (blockIdx.x & 127) * BLK_ROWS;      // LHW offset
    const size_t inBase = (size_t)bq * (Cc * LHWc) + p0;

    // ---- stage biased c2 into LDS ----
    c2bs[tid]       = c2g[tid] + 0.25f;
    c2bs[tid + 512] = c2g[tid + 512] + 0.25f;

    // ---- stage X[128 rows][64 d] into LDS (coalesced) ----
#pragma unroll
    for (int i = 0; i < 16; ++i) {
        int idx = i * 512 + tid;
        int d = idx >> 7, row = idx & 127;
        xs[row][d] = in[inBase + (size_t)d * LHWc + row];
    }
    __syncthreads();

    // ---- x2 per row: exact ascending fma chain (used only in recheck) ----
    if (tid < BLK_ROWS) {
        float s = 0.f;
#pragma unroll
        for (int d = 0; d < Dc; ++d) s = __builtin_fmaf(xs[tid][d], xs[tid][d], s);
        xs2[tid] = s;
    }

    // ---- build A fragments (bf16 hi/lo split) ----
    short8 xh[2][2], xl[2][2];   // [row-tile][kt]
#pragma unroll
    for (int t = 0; t < 2; ++t) {
#pragma unroll
        for (int kt = 0; kt < 2; ++kt) {
            const float* px = &xs[wrow0 + t * 16 + col][kt * 32 + g * 8];
            f32x4 v0 = *(const f32x4*)px;
            f32x4 v1 = *(const f32x4*)(px + 4);
            short8 h8, l8;
#pragma unroll
            for (int j = 0; j < 4; ++j) {
                unsigned short ha = f2bf(v0[j]);
                h8[j]     = (short)ha;
                l8[j]     = (short)f2bf(v0[j] - bf2f(ha));
                unsigned short hb = f2bf(v1[j]);
                h8[4 + j] = (short)hb;
                l8[4 + j] = (short)f2bf(v1[j] - bf2f(hb));
            }
            xh[t][kt] = h8; xl[t][kt] = l8;
        }
    }

    // ---- streaming top-2 state per (tile, reg) slot ----
    float bV[2][4], sV[2][4];
    int   bK[2][4], sK[2][4];
#pragma unroll
    for (int t = 0; t < 2; ++t)
#pragma unroll
        for (int r = 0; r < 4; ++r) {
            bV[t][r] = 3.4e38f; sV[t][r] = 3.4e38f; bK[t][r] = 0; sK[t][r] = 0;
        }

    const unsigned short* bhp = cbh + (size_t)(kbase + col) * Dc + g * 8;
    const unsigned short* blp = cbl + (size_t)(kbase + col) * Dc + g * 8;

    short8 bh0 = *(const short8*)(bhp);
    short8 bh1 = *(const short8*)(bhp + 32);
    short8 bl0 = *(const short8*)(blp);
    short8 bl1 = *(const short8*)(blp + 32);

    int kcolv = kbase + col;

#pragma unroll 1
    for (int ct = 0; ct < 32; ++ct) {
        const float c2bv = c2bs[kcolv];      // issued early, hides under MFMA
        short8 ch0 = bh0, ch1 = bh1, cl0 = bl0, cl1 = bl1;
        bhp += 16 * Dc; blp += 16 * Dc;
        if (ct < 31) {                       // 1-deep register prefetch
            bh0 = *(const short8*)(bhp);
            bh1 = *(const short8*)(bhp + 32);
            bl0 = *(const short8*)(blp);
            bl1 = *(const short8*)(blp + 32);
        }

        f32x4 acc0 = {0.f, 0.f, 0.f, 0.f};
        f32x4 acc1 = {0.f, 0.f, 0.f, 0.f};
        // interleaved acc0/acc1: dependent-MFMA distance 2
        acc0 = __builtin_amdgcn_mfma_f32_16x16x32_bf16(xh[0][0], ch0, acc0, 0, 0, 0);
        acc1 = __builtin_amdgcn_mfma_f32_16x16x32_bf16(xh[1][0], ch0, acc1, 0, 0, 0);
        acc0 = __builtin_amdgcn_mfma_f32_16x16x32_bf16(xh[0][1], ch1, acc0, 0, 0, 0);
        acc1 = __builtin_amdgcn_mfma_f32_16x16x32_bf16(xh[1][1], ch1, acc1, 0, 0, 0);
        acc0 = __builtin_amdgcn_mfma_f32_16x16x32_bf16(xh[0][0], cl0, acc0, 0, 0, 0);
        acc1 = __builtin_amdgcn_mfma_f32_16x16x32_bf16(xh[1][0], cl0, acc1, 0, 0, 0);
        acc0 = __builtin_amdgcn_mfma_f32_16x16x32_bf16(xh[0][1], cl1, acc0, 0, 0, 0);
        acc1 = __builtin_amdgcn_mfma_f32_16x16x32_bf16(xh[1][1], cl1, acc1, 0, 0, 0);
        acc0 = __builtin_amdgcn_mfma_f32_16x16x32_bf16(xl[0][0], ch0, acc0, 0, 0, 0);
        acc1 = __builtin_amdgcn_mfma_f32_16x16x32_bf16(xl[1][0], ch0, acc1, 0, 0, 0);
        acc0 = __builtin_amdgcn_mfma_f32_16x16x32_bf16(xl[0][1], ch1, acc0, 0, 0, 0);
        acc1 = __builtin_amdgcn_mfma_f32_16x16x32_bf16(xl[1][1], ch1, acc1, 0, 0, 0);

        // argmin_k d2 == argmin_k (c2[k]+0.25 - 2*dot): x2 folded out
#pragma unroll
        for (int t = 0; t < 2; ++t) {
#pragma unroll
            for (int r = 0; r < 4; ++r) {
                float a  = (t == 0) ? acc0[r] : acc1[r];
                float v  = __builtin_fmaf(-2.f, a, c2bv);
                bool  c1 = v < bV[t][r];
                float nb  = c1 ? v : bV[t][r];
                int   nbk = c1 ? kcolv : bK[t][r];
                float mx  = c1 ? bV[t][r] : v;
                int   mxk = c1 ? bK[t][r] : kcolv;
                bool  c2_ = mx < sV[t][r];
                sV[t][r] = c2_ ? mx : sV[t][r];
                sK[t][r] = c2_ ? mxk : sK[t][r];
                bV[t][r] = nb; bK[t][r] = nbk;
            }
        }
        kcolv += 16;
    }

    // ---- butterfly top-2 merge across the 16 lanes sharing a row ----
#pragma unroll
    for (int m = 1; m < 16; m <<= 1) {
#pragma unroll
        for (int t = 0; t < 2; ++t) {
#pragma unroll
            for (int r = 0; r < 4; ++r) {
                float ob  = __shfl_xor(bV[t][r], m, 64);
                int   obk = __shfl_xor(bK[t][r], m, 64);
                float os  = __shfl_xor(sV[t][r], m, 64);
                int   osk = __shfl_xor(sK[t][r], m, 64);
                bool  c1 = ob < bV[t][r];
                float nb  = c1 ? ob : bV[t][r];
                int   nbk = c1 ? obk : bK[t][r];
                float mx  = c1 ? bV[t][r] : ob;
                int   mxk = c1 ? bK[t][r] : obk;
                bool  c3 = os < sV[t][r];
                float ms  = c3 ? os : sV[t][r];
                int   msk = c3 ? osk : sK[t][r];
                bool  c4 = mx < ms;
                sV[t][r] = c4 ? mx : ms;
                sK[t][r] = c4 ? mxk : msk;
                bV[t][r] = nb; bK[t][r] = nbk;
            }
        }
    }
    if (col == 0) {
#pragma unroll
        for (int t = 0; t < 2; ++t)
#pragma unroll
            for (int r = 0; r < 4; ++r)
                cand[wrow0 + t * 16 + g * 4 + r][qq] =
                    (unsigned)bK[t][r] | ((unsigned)sK[t][r] << 16);
    }
    __syncthreads();

    // ---- exact recheck: 4 candidates/row, 1 thread per (row, candidate) ----
    {
        const int row = tid >> 2;
        const int ci  = tid & 3;
        const unsigned cd = cand[row][ci >> 1];
        const int k = (ci & 1) ? (int)(cd >> 16) : (int)(cd & 0xFFFFu);
        const float* cbr = codebook + (size_t)k * Dc;
        float a = 0.f;
#pragma unroll
        for (int d4 = 0; d4 < 16; ++d4) {
            f32x4 cv = *(const f32x4*)(cbr + d4 * 4);
            const float* xr = &xs[row][d4 * 4];
            a = __builtin_fmaf(xr[0], cv[0], a);
            a = __builtin_fmaf(xr[1], cv[1], a);
            a = __builtin_fmaf(xr[2], cv[2], a);
            a = __builtin_fmaf(xr[3], cv[3], a);
        }
        float d2 = __builtin_fmaf(-2.f, a, xs2[row]) + c2g[k];
        unsigned long long pk =
            ((unsigned long long)__float_as_uint(d2) << 32) | (unsigned)k;
#pragma unroll
        for (int m = 1; m < 4; m <<= 1) {
            unsigned long long o = __shfl_xor(pk, m, 64);
            pk = o < pk ? o : pk;            // min d2, ties -> lowest k
        }
        if (ci == 0) {
            const int kwin = (int)(pk & 0xFFFFFFFFu);
            kws[row] = kwin;
            out[OFF_IDX + (size_t)blockIdx.x * BLK_ROWS + row] = (float)kwin;
        }
    }
    __syncthreads();

    // ---- quantized write + loss: 4 threads per row, 16 channels each ----
    {
        const int row = tid & 127;
        const int cp  = tid >> 7;            // 0..3
        const int kw  = kws[row];
        const float* cbw = codebook + (size_t)kw * Dc + cp * 16;
        float* qout = out + inBase + row;
        float ls = 0.f;
#pragma unroll
        for (int j = 0; j < 16; ++j) {
            const int c = cp * 16 + j;
            float qv = cbw[j];
            qout[(size_t)c * LHWc] = qv;     // coalesced across lanes per c
            float e = qv - xs[row][c];
            ls = __builtin_fmaf(e, e, ls);
        }
#pragma unroll
        for (int off = 32; off > 0; off >>= 1) ls += __shfl_down(ls, off, 64);
        if (lane == 0) atomicAdd(&out[OFF_LOSS], ls * (1.25f / (float)QSIZE));
    }
}

extern "C" void kernel_launch(void* const* d_in, const int* in_sizes, int n_in,
                              void* d_out, int out_size, void* d_ws, size_t ws_size,
                              hipStream_t stream) {
    const float* in = (const float*)d_in[0];   // [4,64,16,32,32] f32
    const float* cb = (const float*)d_in[1];   // [1024,64] f32
    float* out = (float*)d_out;
    (void)in_sizes; (void)n_in; (void)out_size; (void)ws_size;

    unsigned short* cbh = (unsigned short*)d_ws;                 // 128 KB
    unsigned short* cbl = cbh + (size_t)Kc * Dc;                 // 128 KB
    float*          c2  = (float*)(cbl + (size_t)Kc * Dc);       // 4 KB

    vq_prep<<<dim3(16), dim3(256), 0, stream>>>(cb, out, cbh, cbl, c2);
    vq_main<<<dim3(Nc / BLK_ROWS), dim3(512), 0, stream>>>(in, cb, cbh, cbl, c2, out);
}